// Round 8
// baseline (209.553 us; speedup 1.0000x reference)
//
#include <hip/hip_runtime.h>

#define HW    16384   // 128*128
#define Wh    128
#define Cin   64
#define C2    32
#define HW4   4096    // 64*64

typedef short short8 __attribute__((ext_vector_type(8)));     // 8 bf16 = 4 VGPRs
typedef float float4v __attribute__((ext_vector_type(4)));
typedef unsigned uint4v __attribute__((ext_vector_type(4)));

#define LOG2E 1.44269504f
#define OFFE  43.2808512f   // 30*log2(e): exp(s-30) == exp2(s*log2e - OFFE)

__device__ __forceinline__ unsigned pack2bf16(float lo, float hi) {
  unsigned ul = __builtin_bit_cast(unsigned, lo);
  unsigned uh = __builtin_bit_cast(unsigned, hi);
  ul = (ul + 0x7fffu + ((ul >> 16) & 1u)) >> 16;
  uh = (uh + 0x7fffu + ((uh >> 16) & 1u)) & 0xffff0000u;
  return ul | uh;
}
__device__ __forceinline__ unsigned short f2bf(float f) {
  unsigned u = __builtin_bit_cast(unsigned, f);
  return (unsigned short)((u + 0x7fffu + ((u >> 16) & 1u)) >> 16);
}
// RTZ-truncate two fp32 to bf16, lo in [15:0], hi in [31:16]
__device__ __forceinline__ unsigned packtrunc(float lo, float hi) {
  return __builtin_amdgcn_perm(__builtin_bit_cast(unsigned, hi),
                               __builtin_bit_cast(unsigned, lo), 0x07060302u);
}

// ---------------------------------------------------------------------------
// Kernel 0: weight repack. wAll[og][c][24] = {theta(8, x log2e), phi(8), g(8)}
// contiguous per c -> conv inner loop reads 96 B/c via wide s_loads.
// ---------------------------------------------------------------------------
__global__ __launch_bounds__(256) void repack_w_kern(
    const float* __restrict__ wt, const float* __restrict__ bt,
    const float* __restrict__ wp, const float* __restrict__ bp,
    const float* __restrict__ wg, const float* __restrict__ bg,
    float* __restrict__ wAll, float* __restrict__ bAll) {
  int idx = blockIdx.x * 256 + threadIdx.x;
  if (idx < 6144) {
    int og = idx / 1536, rem = idx % 1536;
    int c = rem / 24, j = rem % 24;
    int o = og * 8 + (j & 7);
    float v;
    if (j < 8)       v = wt[o * Cin + c] * LOG2E;
    else if (j < 16) v = wp[o * Cin + c];
    else             v = wg[o * Cin + c];
    wAll[idx] = v;
  } else if (idx < 6240) {
    int i2 = idx - 6144;
    int og = i2 / 24, j = i2 % 24;
    int o = og * 8 + (j & 7);
    bAll[i2] = (j < 8) ? bt[o] * LOG2E : (j < 16 ? bp[o] : bg[o]);
  }
}

// ---------------------------------------------------------------------------
// Kernel 1: FUSED theta+phi+g conv (+2x2 maxpool), 2 PIXELS PER THREAD.
// Thread handles the horizontal pool pair (cols 2j,2j+1) of one full-res row;
// vertical pool mate is lane^1. float2 x-loads; 48 FMA per 24 weight s_loads.
// Outputs: Q bf16 [b][p][32] (theta, pre-scaled log2e),
//          K bf16 with per-32-tile row perm ((k&4)<<2)+((k>>3)<<2)+(k&3),
//          Vt bf16 [b][ch][4096], coalesced dword stores via LDS transpose.
// ---------------------------------------------------------------------------
__global__ __launch_bounds__(256) void conv_qkv_kern(
    const float* __restrict__ x, const float* __restrict__ wAll,
    const float* __restrict__ bAll, unsigned short* __restrict__ Q,
    unsigned short* __restrict__ K, unsigned short* __restrict__ Vt) {
  __shared__ unsigned short smV[8][128];         // 2 KB
  int tid = threadIdx.x;
  int l = tid & 63, w = tid >> 6;
  int og = blockIdx.y, b = blockIdx.z;
  int ppl = w * 32 + (l >> 1);                   // local pooled idx 0..127
  int pp = blockIdx.x * 128 + ppl;               // global pooled pixel
  int i = pp >> 6, j = pp & 63;
  int row = 2 * i + (l & 1);
  int colp = 2 * j;
  const float* xb = x + (size_t)b * Cin * HW + row * Wh + colp;
  const float* wc = wAll + og * 1536;            // uniform -> s_load
  const float* bb = bAll + og * 24;
  float acc[48];                                 // [cout 24][px 2]
#pragma unroll
  for (int k = 0; k < 24; ++k) { acc[2 * k] = bb[k]; acc[2 * k + 1] = bb[k]; }
  for (int c = 0; c < Cin; ++c) {
    float2 xv = *(const float2*)(xb + (size_t)c * HW);   // 2 coalesced rows
#pragma unroll
    for (int k = 0; k < 24; ++k) {
      float wv = wc[c * 24 + k];
      acc[2 * k]     = fmaf(wv, xv.x, acc[2 * k]);
      acc[2 * k + 1] = fmaf(wv, xv.y, acc[2 * k + 1]);
    }
  }
  // theta -> Q for both pixels
  {
    int p0 = row * Wh + colp;
    uint4 u0, u1;
    u0.x = pack2bf16(acc[0], acc[2]);  u0.y = pack2bf16(acc[4], acc[6]);
    u0.z = pack2bf16(acc[8], acc[10]); u0.w = pack2bf16(acc[12], acc[14]);
    u1.x = pack2bf16(acc[1], acc[3]);  u1.y = pack2bf16(acc[5], acc[7]);
    u1.z = pack2bf16(acc[9], acc[11]); u1.w = pack2bf16(acc[13], acc[15]);
    *(uint4*)(Q + ((size_t)b * HW + p0) * C2 + og * 8) = u0;
    *(uint4*)(Q + ((size_t)b * HW + p0 + 1) * C2 + og * 8) = u1;
  }
  // maxpool: horizontal in-register, vertical via lane^1
  float aP[8], aG[8];
#pragma unroll
  for (int o = 0; o < 8; ++o) {
    float vp = fmaxf(acc[16 + 2 * o], acc[16 + 2 * o + 1]);
    float vg = fmaxf(acc[32 + 2 * o], acc[32 + 2 * o + 1]);
    aP[o] = fmaxf(vp, __shfl_xor(vp, 1));
    aG[o] = fmaxf(vg, __shfl_xor(vg, 1));
  }
  if ((l & 1) == 0) {
    int loc = pp & 31, tile = pp >> 5;
    int prow = ((loc & 4) << 2) + ((loc >> 3) << 2) + (loc & 3);   // S^T perm
    uint4 up;
    up.x = pack2bf16(aP[0], aP[1]); up.y = pack2bf16(aP[2], aP[3]);
    up.z = pack2bf16(aP[4], aP[5]); up.w = pack2bf16(aP[6], aP[7]);
    *(uint4*)(K + ((size_t)b * HW4 + tile * 32 + prow) * C2 + og * 8) = up;
#pragma unroll
    for (int o = 0; o < 8; ++o) smV[o][ppl] = f2bf(aG[o]);
  }
  __syncthreads();
  // coalesced V store: thread t -> channel t>>5, two dwords (4 keys)
  {
    int ch = tid >> 5, idx = tid & 31;
    unsigned v0 = ((unsigned*)smV)[ch * 64 + idx];
    unsigned v1 = ((unsigned*)smV)[ch * 64 + idx + 32];
    unsigned short* vdst = Vt + (size_t)b * C2 * HW4 +
                           (size_t)(og * 8 + ch) * HW4 + blockIdx.x * 128;
    *(unsigned*)(vdst + 2 * idx) = v0;
    *(unsigned*)(vdst + 2 * (idx + 32)) = v1;
  }
}

// ---------------------------------------------------------------------------
// Kernel 2: MFMA flash attention — register-only loop + 2-deep prefetch.
// S^T trick (K rows pre-permuted): P emerges in the PV A-layout in registers.
// Per 32-key tile: 4 prefetched loads, 10 MFMA (4 QK + 4 PV + 2 ones-MFMA
// for the row sums l — C-layout of ones-MFMA aligns y2[r] exactly with
// y0[r]'s q-row), 16 exp2, 8 v_perm. 4-way key split merged via LDS at end.
// ---------------------------------------------------------------------------
struct KVT { short8 ka, kh, va, vh; };

__device__ __forceinline__ KVT ldkv(const unsigned short* kt,
                                    const unsigned short* vt,
                                    int l16, int quad) {
  KVT r;
  r.ka = *(const short8*)(kt + (size_t)l16 * C2 + quad * 8);
  r.kh = *(const short8*)(kt + (size_t)(16 + l16) * C2 + quad * 8);
  r.va = *(const short8*)(vt + (size_t)l16 * HW4 + quad * 8);
  r.vh = *(const short8*)(vt + (size_t)(16 + l16) * HW4 + quad * 8);
  return r;
}

__global__ __launch_bounds__(256, 6) void attn_mfma_kern(
    const unsigned short* __restrict__ Qb, const unsigned short* __restrict__ Kb,
    const unsigned short* __restrict__ Vt, float* __restrict__ Y) {
  __shared__ float smY[3][32][33];
  __shared__ float smL[4][32];
  int lane = threadIdx.x & 63;
  int wv = threadIdx.x >> 6;
  int quad = lane >> 4, l16 = lane & 15;
  int b = blockIdx.y;
  int qrow0 = blockIdx.x * 32;

  short8 qf0 = *(const short8*)(Qb + ((size_t)b * HW + qrow0 + l16) * C2 + quad * 8);
  short8 qf1 = *(const short8*)(Qb + ((size_t)b * HW + qrow0 + 16 + l16) * C2 + quad * 8);
  const unsigned short* kb = Kb + ((size_t)b * HW4 + wv * 1024) * C2;
  const unsigned short* vb = Vt + (size_t)b * C2 * HW4 + wv * 1024;

  short8 ones;
#pragma unroll
  for (int i = 0; i < 8; ++i) ones[i] = (short)0x3F80;  // bf16 1.0

  float4v z = {0.f, 0.f, 0.f, 0.f};
  float4v y00 = z, y10 = z, y20 = z, y01 = z, y11 = z, y21 = z;
  float4v moff = {-OFFE, -OFFE, -OFFE, -OFFE};

  KVT cur = ldkv(kb, vb, l16, quad);
  for (int t = 0; t < 32; ++t) {
    int tn = (t < 31) ? (t + 1) : 31;
    KVT nxt = ldkv(kb + (size_t)tn * 32 * C2, vb + tn * 32, l16, quad);

    float4v s00 = __builtin_amdgcn_mfma_f32_16x16x32_bf16(cur.ka, qf0, moff, 0, 0, 0);
    float4v s10 = __builtin_amdgcn_mfma_f32_16x16x32_bf16(cur.kh, qf0, moff, 0, 0, 0);
    float4v s01 = __builtin_amdgcn_mfma_f32_16x16x32_bf16(cur.ka, qf1, moff, 0, 0, 0);
    float4v s11 = __builtin_amdgcn_mfma_f32_16x16x32_bf16(cur.kh, qf1, moff, 0, 0, 0);

    {
      float e0 = __builtin_amdgcn_exp2f(s00[0]), e1 = __builtin_amdgcn_exp2f(s00[1]);
      float e2 = __builtin_amdgcn_exp2f(s00[2]), e3 = __builtin_amdgcn_exp2f(s00[3]);
      float f0 = __builtin_amdgcn_exp2f(s10[0]), f1 = __builtin_amdgcn_exp2f(s10[1]);
      float f2 = __builtin_amdgcn_exp2f(s10[2]), f3 = __builtin_amdgcn_exp2f(s10[3]);
      uint4v d = {packtrunc(e0, e1), packtrunc(e2, e3),
                  packtrunc(f0, f1), packtrunc(f2, f3)};
      short8 pf0 = __builtin_bit_cast(short8, d);
      y00 = __builtin_amdgcn_mfma_f32_16x16x32_bf16(pf0, cur.va, y00, 0, 0, 0);
      y10 = __builtin_amdgcn_mfma_f32_16x16x32_bf16(pf0, cur.vh, y10, 0, 0, 0);
      y20 = __builtin_amdgcn_mfma_f32_16x16x32_bf16(pf0, ones,   y20, 0, 0, 0);
    }
    {
      float e0 = __builtin_amdgcn_exp2f(s01[0]), e1 = __builtin_amdgcn_exp2f(s01[1]);
      float e2 = __builtin_amdgcn_exp2f(s01[2]), e3 = __builtin_amdgcn_exp2f(s01[3]);
      float f0 = __builtin_amdgcn_exp2f(s11[0]), f1 = __builtin_amdgcn_exp2f(s11[1]);
      float f2 = __builtin_amdgcn_exp2f(s11[2]), f3 = __builtin_amdgcn_exp2f(s11[3]);
      uint4v d = {packtrunc(e0, e1), packtrunc(e2, e3),
                  packtrunc(f0, f1), packtrunc(f2, f3)};
      short8 pf1 = __builtin_bit_cast(short8, d);
      y01 = __builtin_amdgcn_mfma_f32_16x16x32_bf16(pf1, cur.va, y01, 0, 0, 0);
      y11 = __builtin_amdgcn_mfma_f32_16x16x32_bf16(pf1, cur.vh, y11, 0, 0, 0);
      y21 = __builtin_amdgcn_mfma_f32_16x16x32_bf16(pf1, ones,   y21, 0, 0, 0);
    }
    cur = nxt;
  }

  // y20[r]/y21[r] = per-quarter row sums l, already aligned to y00[r] rows.
  if (l16 == 0) {
#pragma unroll
    for (int r = 0; r < 4; ++r) {
      smL[wv][quad * 4 + r] = y20[r];
      smL[wv][16 + quad * 4 + r] = y21[r];
    }
  }
  if (wv > 0) {
    int pi = wv - 1;
#pragma unroll
    for (int r = 0; r < 4; ++r) {
      int lr0 = quad * 4 + r, lr1 = lr0 + 16;
      smY[pi][lr0][l16] = y00[r];  smY[pi][lr0][16 + l16] = y10[r];
      smY[pi][lr1][l16] = y01[r];  smY[pi][lr1][16 + l16] = y11[r];
    }
  }
  __syncthreads();
  if (wv == 0) {
#pragma unroll
    for (int r = 0; r < 4; ++r) {
      int lr0 = quad * 4 + r, lr1 = lr0 + 16;
      float a0 = y00[r] + smY[0][lr0][l16] + smY[1][lr0][l16] + smY[2][lr0][l16];
      float a1 = y10[r] + smY[0][lr0][16 + l16] + smY[1][lr0][16 + l16] + smY[2][lr0][16 + l16];
      float c0 = y01[r] + smY[0][lr1][l16] + smY[1][lr1][l16] + smY[2][lr1][l16];
      float c1 = y11[r] + smY[0][lr1][16 + l16] + smY[1][lr1][16 + l16] + smY[2][lr1][16 + l16];
      float L0 = smL[0][lr0] + smL[1][lr0] + smL[2][lr0] + smL[3][lr0];
      float L1 = smL[0][lr1] + smL[1][lr1] + smL[2][lr1] + smL[3][lr1];
      float inv0 = 1.f / L0, inv1 = 1.f / L1;
      size_t row0 = (size_t)b * HW + qrow0 + lr0;
      size_t row1 = (size_t)b * HW + qrow0 + lr1;
      Y[row0 * C2 + l16]      = a0 * inv0;
      Y[row0 * C2 + 16 + l16] = a1 * inv0;
      Y[row1 * C2 + l16]      = c0 * inv1;
      Y[row1 * C2 + 16 + l16] = c1 * inv1;
    }
  }
}

// ---------------------------------------------------------------------------
// Kernel 3: output conv (32->64) + bias + residual; cog from blockIdx.y.
// ---------------------------------------------------------------------------
__global__ __launch_bounds__(256) void conv_out_kern(
    const float* __restrict__ Y, const float* __restrict__ x,
    const float* __restrict__ w, const float* __restrict__ bias,
    float* __restrict__ out) {
  int p = blockIdx.x * 256 + threadIdx.x;
  int cog = blockIdx.y, b = blockIdx.z;
  float y[C2];
  const float4* yp4 = (const float4*)(Y + ((size_t)b * HW + p) * C2);
#pragma unroll
  for (int i = 0; i < 8; ++i) {
    float4 t = yp4[i];
    y[4 * i] = t.x; y[4 * i + 1] = t.y; y[4 * i + 2] = t.z; y[4 * i + 3] = t.w;
  }
  const float* xb = x + (size_t)b * Cin * HW + p;
  float* ob = out + (size_t)b * Cin * HW + p;
#pragma unroll
  for (int i = 0; i < 16; ++i) {
    int co = cog * 16 + i;
    float s = bias[co];
#pragma unroll
    for (int o = 0; o < C2; ++o) s = fmaf(w[co * C2 + o], y[o], s);
    ob[(size_t)co * HW] = s + xb[(size_t)co * HW];
  }
}

// ---------------------------------------------------------------------------
extern "C" void kernel_launch(void* const* d_in, const int* in_sizes, int n_in,
                              void* d_out, int out_size, void* d_ws, size_t ws_size,
                              hipStream_t stream) {
  const float* x       = (const float*)d_in[0];
  const float* w_theta = (const float*)d_in[1];
  const float* b_theta = (const float*)d_in[2];
  const float* w_phi   = (const float*)d_in[3];
  const float* b_phi   = (const float*)d_in[4];
  const float* w_g     = (const float*)d_in[5];
  const float* b_g     = (const float*)d_in[6];
  const float* w_out   = (const float*)d_in[7];
  const float* b_out   = (const float*)d_in[8];
  float* out = (float*)d_out;

  float* Yws = (float*)d_ws;                                   // 8 MB fp32
  unsigned short* Qb = (unsigned short*)(Yws + (size_t)4 * HW * C2);
  unsigned short* Kb = Qb + (size_t)4 * HW * C2;
  unsigned short* Vt = Kb + (size_t)4 * HW4 * C2;
  float* wAll = (float*)(Vt + (size_t)4 * HW4 * C2);           // 6144 f
  float* bAll = wAll + 6144;                                   // 96 f

  repack_w_kern<<<25, 256, 0, stream>>>(w_theta, b_theta, w_phi, b_phi,
                                        w_g, b_g, wAll, bAll);
  conv_qkv_kern<<<dim3(32, 4, 4), 256, 0, stream>>>(x, wAll, bAll, Qb, Kb, Vt);
  attn_mfma_kern<<<dim3(HW / 32, 4), 256, 0, stream>>>(Qb, Kb, Vt, Yws);
  conv_out_kern<<<dim3(64, 4, 4), 256, 0, stream>>>(Yws, x, w_out, b_out, out);
}

// Round 9
// 202.378 us; speedup vs baseline: 1.0355x; 1.0355x over previous
//
#include <hip/hip_runtime.h>

#define HW    16384   // 128*128
#define Wh    128
#define Cin   64
#define C2    32
#define HW4   4096    // 64*64

typedef short short8 __attribute__((ext_vector_type(8)));     // 8 bf16 = 4 VGPRs
typedef float float4v __attribute__((ext_vector_type(4)));
typedef unsigned uint4v __attribute__((ext_vector_type(4)));

#define LOG2E 1.44269504f
#define OFFE  43.2808512f   // 30*log2(e): exp(s-30) == exp2(s*log2e - OFFE)

__device__ __forceinline__ unsigned pack2bf16(float lo, float hi) {
  unsigned ul = __builtin_bit_cast(unsigned, lo);
  unsigned uh = __builtin_bit_cast(unsigned, hi);
  ul = (ul + 0x7fffu + ((ul >> 16) & 1u)) >> 16;
  uh = (uh + 0x7fffu + ((uh >> 16) & 1u)) & 0xffff0000u;
  return ul | uh;
}
__device__ __forceinline__ unsigned short f2bf(float f) {
  unsigned u = __builtin_bit_cast(unsigned, f);
  return (unsigned short)((u + 0x7fffu + ((u >> 16) & 1u)) >> 16);
}
// RTZ-truncate two fp32 to bf16, lo in [15:0], hi in [31:16]
__device__ __forceinline__ unsigned packtrunc(float lo, float hi) {
  return __builtin_amdgcn_perm(__builtin_bit_cast(unsigned, hi),
                               __builtin_bit_cast(unsigned, lo), 0x07060302u);
}

// ---------------------------------------------------------------------------
// Kernel 0: weight repack. wAll[og][c][24] = {theta(8, x log2e), phi(8), g(8)}
// contiguous per c -> conv inner loop reads 96 B/c via wide s_loads.
// ---------------------------------------------------------------------------
__global__ __launch_bounds__(256) void repack_w_kern(
    const float* __restrict__ wt, const float* __restrict__ bt,
    const float* __restrict__ wp, const float* __restrict__ bp,
    const float* __restrict__ wg, const float* __restrict__ bg,
    float* __restrict__ wAll, float* __restrict__ bAll) {
  int idx = blockIdx.x * 256 + threadIdx.x;
  if (idx < 6144) {
    int og = idx / 1536, rem = idx % 1536;
    int c = rem / 24, j = rem % 24;
    int o = og * 8 + (j & 7);
    float v;
    if (j < 8)       v = wt[o * Cin + c] * LOG2E;
    else if (j < 16) v = wp[o * Cin + c];
    else             v = wg[o * Cin + c];
    wAll[idx] = v;
  } else if (idx < 6240) {
    int i2 = idx - 6144;
    int og = i2 / 24, j = i2 % 24;
    int o = og * 8 + (j & 7);
    bAll[i2] = (j < 8) ? bt[o] * LOG2E : (j < 16 ? bp[o] : bg[o]);
  }
}

// ---------------------------------------------------------------------------
// Kernel 1: FUSED theta+phi+g conv (+2x2 maxpool), 2 px/thread, with an
// 8-DEEP EXPLICIT LOAD PIPELINE on the c-loop (8 float2 loads in flight
// before the FMA block — the conv was load-latency-bound, not FLOP-bound).
// ---------------------------------------------------------------------------
__global__ __launch_bounds__(256) void conv_qkv_kern(
    const float* __restrict__ x, const float* __restrict__ wAll,
    const float* __restrict__ bAll, unsigned short* __restrict__ Q,
    unsigned short* __restrict__ K, unsigned short* __restrict__ Vt) {
  __shared__ unsigned short smV[8][128];         // 2 KB
  int tid = threadIdx.x;
  int l = tid & 63, w = tid >> 6;
  int og = blockIdx.y, b = blockIdx.z;
  int ppl = w * 32 + (l >> 1);                   // local pooled idx 0..127
  int pp = blockIdx.x * 128 + ppl;               // global pooled pixel
  int i = pp >> 6, j = pp & 63;
  int row = 2 * i + (l & 1);
  int colp = 2 * j;
  const float* xb = x + (size_t)b * Cin * HW + row * Wh + colp;
  const float* wc = wAll + og * 1536;            // uniform -> s_load
  const float* bb = bAll + og * 24;
  float acc[48];                                 // [cout 24][px 2]
#pragma unroll
  for (int k = 0; k < 24; ++k) { acc[2 * k] = bb[k]; acc[2 * k + 1] = bb[k]; }
  for (int cb = 0; cb < Cin; cb += 8) {
    float2 xv[8];
#pragma unroll
    for (int u = 0; u < 8; ++u)                  // 8 independent loads in flight
      xv[u] = *(const float2*)(xb + (size_t)(cb + u) * HW);
#pragma unroll
    for (int u = 0; u < 8; ++u) {
#pragma unroll
      for (int k = 0; k < 24; ++k) {
        float wv = wc[(cb + u) * 24 + k];
        acc[2 * k]     = fmaf(wv, xv[u].x, acc[2 * k]);
        acc[2 * k + 1] = fmaf(wv, xv[u].y, acc[2 * k + 1]);
      }
    }
  }
  // theta -> Q for both pixels
  {
    int p0 = row * Wh + colp;
    uint4 u0, u1;
    u0.x = pack2bf16(acc[0], acc[2]);  u0.y = pack2bf16(acc[4], acc[6]);
    u0.z = pack2bf16(acc[8], acc[10]); u0.w = pack2bf16(acc[12], acc[14]);
    u1.x = pack2bf16(acc[1], acc[3]);  u1.y = pack2bf16(acc[5], acc[7]);
    u1.z = pack2bf16(acc[9], acc[11]); u1.w = pack2bf16(acc[13], acc[15]);
    *(uint4*)(Q + ((size_t)b * HW + p0) * C2 + og * 8) = u0;
    *(uint4*)(Q + ((size_t)b * HW + p0 + 1) * C2 + og * 8) = u1;
  }
  // maxpool: horizontal in-register, vertical via lane^1
  float aP[8], aG[8];
#pragma unroll
  for (int o = 0; o < 8; ++o) {
    float vp = fmaxf(acc[16 + 2 * o], acc[16 + 2 * o + 1]);
    float vg = fmaxf(acc[32 + 2 * o], acc[32 + 2 * o + 1]);
    aP[o] = fmaxf(vp, __shfl_xor(vp, 1));
    aG[o] = fmaxf(vg, __shfl_xor(vg, 1));
  }
  if ((l & 1) == 0) {
    int loc = pp & 31, tile = pp >> 5;
    int prow = ((loc & 4) << 2) + ((loc >> 3) << 2) + (loc & 3);   // S^T perm
    uint4 up;
    up.x = pack2bf16(aP[0], aP[1]); up.y = pack2bf16(aP[2], aP[3]);
    up.z = pack2bf16(aP[4], aP[5]); up.w = pack2bf16(aP[6], aP[7]);
    *(uint4*)(K + ((size_t)b * HW4 + tile * 32 + prow) * C2 + og * 8) = up;
#pragma unroll
    for (int o = 0; o < 8; ++o) smV[o][ppl] = f2bf(aG[o]);
  }
  __syncthreads();
  // coalesced V store: thread t -> channel t>>5, two dwords (4 keys)
  {
    int ch = tid >> 5, idx = tid & 31;
    unsigned v0 = ((unsigned*)smV)[ch * 64 + idx];
    unsigned v1 = ((unsigned*)smV)[ch * 64 + idx + 32];
    unsigned short* vdst = Vt + (size_t)b * C2 * HW4 +
                           (size_t)(og * 8 + ch) * HW4 + blockIdx.x * 128;
    *(unsigned*)(vdst + 2 * idx) = v0;
    *(unsigned*)(vdst + 2 * (idx + 32)) = v1;
  }
}

// ---------------------------------------------------------------------------
// Kernel 2: MFMA flash attention — register-only loop, 2-deep prefetch,
// __launch_bounds__(256,4): 128-VGPR budget so the prefetch does NOT spill
// (R8 at (256,6) spilled KVT to scratch: +7 MB FETCH/WRITE, regression).
// S^T trick (K rows pre-permuted): P emerges in PV A-layout in registers.
// ones-MFMA computes row sums l on the idle MFMA pipe, row-aligned with y.
// ---------------------------------------------------------------------------
struct KVT { short8 ka, kh, va, vh; };

__device__ __forceinline__ KVT ldkv(const unsigned short* kt,
                                    const unsigned short* vt,
                                    int l16, int quad) {
  KVT r;
  r.ka = *(const short8*)(kt + (size_t)l16 * C2 + quad * 8);
  r.kh = *(const short8*)(kt + (size_t)(16 + l16) * C2 + quad * 8);
  r.va = *(const short8*)(vt + (size_t)l16 * HW4 + quad * 8);
  r.vh = *(const short8*)(vt + (size_t)(16 + l16) * HW4 + quad * 8);
  return r;
}

__global__ __launch_bounds__(256, 4) void attn_mfma_kern(
    const unsigned short* __restrict__ Qb, const unsigned short* __restrict__ Kb,
    const unsigned short* __restrict__ Vt, float* __restrict__ Y) {
  __shared__ float smY[3][32][33];
  __shared__ float smL[4][32];
  int lane = threadIdx.x & 63;
  int wv = threadIdx.x >> 6;
  int quad = lane >> 4, l16 = lane & 15;
  int b = blockIdx.y;
  int qrow0 = blockIdx.x * 32;

  short8 qf0 = *(const short8*)(Qb + ((size_t)b * HW + qrow0 + l16) * C2 + quad * 8);
  short8 qf1 = *(const short8*)(Qb + ((size_t)b * HW + qrow0 + 16 + l16) * C2 + quad * 8);
  const unsigned short* kb = Kb + ((size_t)b * HW4 + wv * 1024) * C2;
  const unsigned short* vb = Vt + (size_t)b * C2 * HW4 + wv * 1024;

  short8 ones;
#pragma unroll
  for (int i = 0; i < 8; ++i) ones[i] = (short)0x3F80;  // bf16 1.0

  float4v z = {0.f, 0.f, 0.f, 0.f};
  float4v y00 = z, y10 = z, y20 = z, y01 = z, y11 = z, y21 = z;
  float4v moff = {-OFFE, -OFFE, -OFFE, -OFFE};

  KVT cur = ldkv(kb, vb, l16, quad);
  for (int t = 0; t < 32; ++t) {
    int tn = (t < 31) ? (t + 1) : 31;
    KVT nxt = ldkv(kb + (size_t)tn * 32 * C2, vb + tn * 32, l16, quad);

    float4v s00 = __builtin_amdgcn_mfma_f32_16x16x32_bf16(cur.ka, qf0, moff, 0, 0, 0);
    float4v s10 = __builtin_amdgcn_mfma_f32_16x16x32_bf16(cur.kh, qf0, moff, 0, 0, 0);
    float4v s01 = __builtin_amdgcn_mfma_f32_16x16x32_bf16(cur.ka, qf1, moff, 0, 0, 0);
    float4v s11 = __builtin_amdgcn_mfma_f32_16x16x32_bf16(cur.kh, qf1, moff, 0, 0, 0);

    {
      float e0 = __builtin_amdgcn_exp2f(s00[0]), e1 = __builtin_amdgcn_exp2f(s00[1]);
      float e2 = __builtin_amdgcn_exp2f(s00[2]), e3 = __builtin_amdgcn_exp2f(s00[3]);
      float f0 = __builtin_amdgcn_exp2f(s10[0]), f1 = __builtin_amdgcn_exp2f(s10[1]);
      float f2 = __builtin_amdgcn_exp2f(s10[2]), f3 = __builtin_amdgcn_exp2f(s10[3]);
      uint4v d = {packtrunc(e0, e1), packtrunc(e2, e3),
                  packtrunc(f0, f1), packtrunc(f2, f3)};
      short8 pf0 = __builtin_bit_cast(short8, d);
      y00 = __builtin_amdgcn_mfma_f32_16x16x32_bf16(pf0, cur.va, y00, 0, 0, 0);
      y10 = __builtin_amdgcn_mfma_f32_16x16x32_bf16(pf0, cur.vh, y10, 0, 0, 0);
      y20 = __builtin_amdgcn_mfma_f32_16x16x32_bf16(pf0, ones,   y20, 0, 0, 0);
    }
    {
      float e0 = __builtin_amdgcn_exp2f(s01[0]), e1 = __builtin_amdgcn_exp2f(s01[1]);
      float e2 = __builtin_amdgcn_exp2f(s01[2]), e3 = __builtin_amdgcn_exp2f(s01[3]);
      float f0 = __builtin_amdgcn_exp2f(s11[0]), f1 = __builtin_amdgcn_exp2f(s11[1]);
      float f2 = __builtin_amdgcn_exp2f(s11[2]), f3 = __builtin_amdgcn_exp2f(s11[3]);
      uint4v d = {packtrunc(e0, e1), packtrunc(e2, e3),
                  packtrunc(f0, f1), packtrunc(f2, f3)};
      short8 pf1 = __builtin_bit_cast(short8, d);
      y01 = __builtin_amdgcn_mfma_f32_16x16x32_bf16(pf1, cur.va, y01, 0, 0, 0);
      y11 = __builtin_amdgcn_mfma_f32_16x16x32_bf16(pf1, cur.vh, y11, 0, 0, 0);
      y21 = __builtin_amdgcn_mfma_f32_16x16x32_bf16(pf1, ones,   y21, 0, 0, 0);
    }
    cur = nxt;
  }

  // y20[r]/y21[r] = per-quarter row sums l, row-aligned with y00[r]/y01[r].
  if (l16 == 0) {
#pragma unroll
    for (int r = 0; r < 4; ++r) {
      smL[wv][quad * 4 + r] = y20[r];
      smL[wv][16 + quad * 4 + r] = y21[r];
    }
  }
  if (wv > 0) {
    int pi = wv - 1;
#pragma unroll
    for (int r = 0; r < 4; ++r) {
      int lr0 = quad * 4 + r, lr1 = lr0 + 16;
      smY[pi][lr0][l16] = y00[r];  smY[pi][lr0][16 + l16] = y10[r];
      smY[pi][lr1][l16] = y01[r];  smY[pi][lr1][16 + l16] = y11[r];
    }
  }
  __syncthreads();
  if (wv == 0) {
#pragma unroll
    for (int r = 0; r < 4; ++r) {
      int lr0 = quad * 4 + r, lr1 = lr0 + 16;
      float a0 = y00[r] + smY[0][lr0][l16] + smY[1][lr0][l16] + smY[2][lr0][l16];
      float a1 = y10[r] + smY[0][lr0][16 + l16] + smY[1][lr0][16 + l16] + smY[2][lr0][16 + l16];
      float c0 = y01[r] + smY[0][lr1][l16] + smY[1][lr1][l16] + smY[2][lr1][l16];
      float c1 = y11[r] + smY[0][lr1][16 + l16] + smY[1][lr1][16 + l16] + smY[2][lr1][16 + l16];
      float L0 = smL[0][lr0] + smL[1][lr0] + smL[2][lr0] + smL[3][lr0];
      float L1 = smL[0][lr1] + smL[1][lr1] + smL[2][lr1] + smL[3][lr1];
      float inv0 = 1.f / L0, inv1 = 1.f / L1;
      size_t row0 = (size_t)b * HW + qrow0 + lr0;
      size_t row1 = (size_t)b * HW + qrow0 + lr1;
      Y[row0 * C2 + l16]      = a0 * inv0;
      Y[row0 * C2 + 16 + l16] = a1 * inv0;
      Y[row1 * C2 + l16]      = c0 * inv1;
      Y[row1 * C2 + 16 + l16] = c1 * inv1;
    }
  }
}

// ---------------------------------------------------------------------------
// Kernel 3: output conv (32->64) + bias + residual; all loads hoisted ahead
// of the compute/store loop (breaks the load->fma->store serial chain).
// ---------------------------------------------------------------------------
__global__ __launch_bounds__(256) void conv_out_kern(
    const float* __restrict__ Y, const float* __restrict__ x,
    const float* __restrict__ w, const float* __restrict__ bias,
    float* __restrict__ out) {
  int p = blockIdx.x * 256 + threadIdx.x;
  int cog = blockIdx.y, b = blockIdx.z;
  const float* xb = x + (size_t)b * Cin * HW + p;
  float xr[16];
#pragma unroll
  for (int i = 0; i < 16; ++i)                   // 16 loads in flight
    xr[i] = xb[(size_t)(cog * 16 + i) * HW];
  float y[C2];
  const float4* yp4 = (const float4*)(Y + ((size_t)b * HW + p) * C2);
#pragma unroll
  for (int i = 0; i < 8; ++i) {
    float4 t = yp4[i];
    y[4 * i] = t.x; y[4 * i + 1] = t.y; y[4 * i + 2] = t.z; y[4 * i + 3] = t.w;
  }
  float* ob = out + (size_t)b * Cin * HW + p;
#pragma unroll
  for (int i = 0; i < 16; ++i) {
    int co = cog * 16 + i;
    float s = bias[co];
#pragma unroll
    for (int o = 0; o < C2; ++o) s = fmaf(w[co * C2 + o], y[o], s);
    ob[(size_t)co * HW] = s + xr[i];
  }
}

// ---------------------------------------------------------------------------
extern "C" void kernel_launch(void* const* d_in, const int* in_sizes, int n_in,
                              void* d_out, int out_size, void* d_ws, size_t ws_size,
                              hipStream_t stream) {
  const float* x       = (const float*)d_in[0];
  const float* w_theta = (const float*)d_in[1];
  const float* b_theta = (const float*)d_in[2];
  const float* w_phi   = (const float*)d_in[3];
  const float* b_phi   = (const float*)d_in[4];
  const float* w_g     = (const float*)d_in[5];
  const float* b_g     = (const float*)d_in[6];
  const float* w_out   = (const float*)d_in[7];
  const float* b_out   = (const float*)d_in[8];
  float* out = (float*)d_out;

  float* Yws = (float*)d_ws;                                   // 8 MB fp32
  unsigned short* Qb = (unsigned short*)(Yws + (size_t)4 * HW * C2);
  unsigned short* Kb = Qb + (size_t)4 * HW * C2;
  unsigned short* Vt = Kb + (size_t)4 * HW4 * C2;
  float* wAll = (float*)(Vt + (size_t)4 * HW4 * C2);           // 6144 f
  float* bAll = wAll + 6144;                                   // 96 f

  repack_w_kern<<<25, 256, 0, stream>>>(w_theta, b_theta, w_phi, b_phi,
                                        w_g, b_g, wAll, bAll);
  conv_qkv_kern<<<dim3(32, 4, 4), 256, 0, stream>>>(x, wAll, bAll, Qb, Kb, Vt);
  attn_mfma_kern<<<dim3(HW / 32, 4), 256, 0, stream>>>(Qb, Kb, Vt, Yws);
  conv_out_kern<<<dim3(64, 4, 4), 256, 0, stream>>>(Yws, x, w_out, b_out, out);
}

// Round 10
// 202.043 us; speedup vs baseline: 1.0372x; 1.0017x over previous
//
#include <hip/hip_runtime.h>

#define HW    16384   // 128*128
#define Wh    128
#define Cin   64
#define C2    32
#define HW4   4096    // 64*64

typedef short short8 __attribute__((ext_vector_type(8)));     // 8 bf16 = 4 VGPRs
typedef float float4v __attribute__((ext_vector_type(4)));
typedef unsigned uint4v __attribute__((ext_vector_type(4)));

#define LOG2E 1.44269504f
#define OFFE  43.2808512f   // 30*log2(e): exp(s-30) == exp2(s*log2e - OFFE)

__device__ __forceinline__ unsigned pack2bf16(float lo, float hi) {
  unsigned ul = __builtin_bit_cast(unsigned, lo);
  unsigned uh = __builtin_bit_cast(unsigned, hi);
  ul = (ul + 0x7fffu + ((ul >> 16) & 1u)) >> 16;
  uh = (uh + 0x7fffu + ((uh >> 16) & 1u)) & 0xffff0000u;
  return ul | uh;
}
__device__ __forceinline__ unsigned short f2bf(float f) {
  unsigned u = __builtin_bit_cast(unsigned, f);
  return (unsigned short)((u + 0x7fffu + ((u >> 16) & 1u)) >> 16);
}
// RTZ-truncate two fp32 to bf16, lo in [15:0], hi in [31:16]
__device__ __forceinline__ unsigned packtrunc(float lo, float hi) {
  return __builtin_amdgcn_perm(__builtin_bit_cast(unsigned, hi),
                               __builtin_bit_cast(unsigned, lo), 0x07060302u);
}

// ---------------------------------------------------------------------------
// Kernel 0: weight repack. wAll[og][c][24] = {theta(8, x log2e), phi(8), g(8)}
// contiguous per c -> conv inner loop reads 96 B/c via wide s_loads.
// ---------------------------------------------------------------------------
__global__ __launch_bounds__(256) void repack_w_kern(
    const float* __restrict__ wt, const float* __restrict__ bt,
    const float* __restrict__ wp, const float* __restrict__ bp,
    const float* __restrict__ wg, const float* __restrict__ bg,
    float* __restrict__ wAll, float* __restrict__ bAll) {
  int idx = blockIdx.x * 256 + threadIdx.x;
  if (idx < 6144) {
    int og = idx / 1536, rem = idx % 1536;
    int c = rem / 24, j = rem % 24;
    int o = og * 8 + (j & 7);
    float v;
    if (j < 8)       v = wt[o * Cin + c] * LOG2E;
    else if (j < 16) v = wp[o * Cin + c];
    else             v = wg[o * Cin + c];
    wAll[idx] = v;
  } else if (idx < 6240) {
    int i2 = idx - 6144;
    int og = i2 / 24, j = i2 % 24;
    int o = og * 8 + (j & 7);
    bAll[i2] = (j < 8) ? bt[o] * LOG2E : (j < 16 ? bp[o] : bg[o]);
  }
}

// ---------------------------------------------------------------------------
// Kernel 1: FUSED theta+phi+g conv (+2x2 maxpool), 1 px/thread (R9's 2px cut
// the grid to 512 blocks = 2 blocks/CU — occupancy-starved). 1024 blocks.
// 8-deep load batch on the c-loop. 2x2 pool mates are lanes {4j..4j+3}.
// ---------------------------------------------------------------------------
__global__ __launch_bounds__(256) void conv_qkv_kern(
    const float* __restrict__ x, const float* __restrict__ wAll,
    const float* __restrict__ bAll, unsigned short* __restrict__ Q,
    unsigned short* __restrict__ K, unsigned short* __restrict__ Vt) {
  __shared__ unsigned short smV[8][64];          // 1 KB
  int tid = threadIdx.x;
  int og = blockIdx.y, b = blockIdx.z;
  int pp = blockIdx.x * 64 + (tid >> 2);         // pooled pixel
  int i = pp >> 6, j = pp & 63;
  int row = 2 * i + ((tid >> 1) & 1);
  int col = 2 * j + (tid & 1);
  int p = row * Wh + col;                        // full-res pixel
  const float* xb = x + (size_t)b * Cin * HW + p;
  const float* wc = wAll + og * 1536;            // uniform -> s_load
  const float* bb = bAll + og * 24;
  float acc[24];
#pragma unroll
  for (int k = 0; k < 24; ++k) acc[k] = bb[k];
  for (int cb = 0; cb < Cin; cb += 8) {
    float xv[8];
#pragma unroll
    for (int u = 0; u < 8; ++u)                  // 8 loads in flight
      xv[u] = xb[(size_t)(cb + u) * HW];
#pragma unroll
    for (int u = 0; u < 8; ++u) {
#pragma unroll
      for (int k = 0; k < 24; ++k)
        acc[k] = fmaf(wc[(cb + u) * 24 + k], xv[u], acc[k]);
    }
  }
  // theta -> Q
  {
    uint4 up;
    up.x = pack2bf16(acc[0], acc[1]); up.y = pack2bf16(acc[2], acc[3]);
    up.z = pack2bf16(acc[4], acc[5]); up.w = pack2bf16(acc[6], acc[7]);
    *(uint4*)(Q + ((size_t)b * HW + p) * C2 + og * 8) = up;
  }
  // 2x2 maxpool across lane-mates {4j..4j+3}
  float aP[8], aG[8];
#pragma unroll
  for (int o = 0; o < 8; ++o) {
    float vp = acc[8 + o], vg = acc[16 + o];
    vp = fmaxf(vp, __shfl_xor(vp, 1)); vp = fmaxf(vp, __shfl_xor(vp, 2));
    vg = fmaxf(vg, __shfl_xor(vg, 1)); vg = fmaxf(vg, __shfl_xor(vg, 2));
    aP[o] = vp; aG[o] = vg;
  }
  if ((tid & 3) == 0) {
    int loc = pp & 31, tile = pp >> 5;
    int prow = ((loc & 4) << 2) + ((loc >> 3) << 2) + (loc & 3);   // S^T perm
    uint4 up;
    up.x = pack2bf16(aP[0], aP[1]); up.y = pack2bf16(aP[2], aP[3]);
    up.z = pack2bf16(aP[4], aP[5]); up.w = pack2bf16(aP[6], aP[7]);
    *(uint4*)(K + ((size_t)b * HW4 + tile * 32 + prow) * C2 + og * 8) = up;
#pragma unroll
    for (int o = 0; o < 8; ++o) smV[o][tid >> 2] = f2bf(aG[o]);
  }
  __syncthreads();
  // coalesced V store: thread t -> channel t>>5, dword t&31 (2 keys)
  {
    int ch = tid >> 5, idx = tid & 31;
    unsigned v = ((unsigned*)smV)[ch * 32 + idx];
    *(unsigned*)(Vt + (size_t)b * C2 * HW4 + (size_t)(og * 8 + ch) * HW4 +
                 blockIdx.x * 64 + 2 * idx) = v;
  }
}

// ---------------------------------------------------------------------------
// Kernel 2: MFMA flash attention — register-only loop, DEPTH-2 prefetch ring
// (cur/n1/nxt: data loaded 2 tiles ahead of use -> ~1800 cyc slack vs L2
// latency; depth-1 in R9 left VMEM-wait exposed). (256,4) = 128-VGPR budget,
// ring fits (~90 VGPR) without spill. S^T trick: P emerges in PV A-layout in
// registers; ones-MFMA computes row sums l on the MFMA pipe, row-aligned.
// ---------------------------------------------------------------------------
struct KVT { short8 ka, kh, va, vh; };

__device__ __forceinline__ KVT ldkv(const unsigned short* kt,
                                    const unsigned short* vt,
                                    int l16, int quad) {
  KVT r;
  r.ka = *(const short8*)(kt + (size_t)l16 * C2 + quad * 8);
  r.kh = *(const short8*)(kt + (size_t)(16 + l16) * C2 + quad * 8);
  r.va = *(const short8*)(vt + (size_t)l16 * HW4 + quad * 8);
  r.vh = *(const short8*)(vt + (size_t)(16 + l16) * HW4 + quad * 8);
  return r;
}

__global__ __launch_bounds__(256, 4) void attn_mfma_kern(
    const unsigned short* __restrict__ Qb, const unsigned short* __restrict__ Kb,
    const unsigned short* __restrict__ Vt, float* __restrict__ Y) {
  __shared__ float smY[3][32][33];
  __shared__ float smL[4][32];
  int lane = threadIdx.x & 63;
  int wv = threadIdx.x >> 6;
  int quad = lane >> 4, l16 = lane & 15;
  int b = blockIdx.y;
  int qrow0 = blockIdx.x * 32;

  short8 qf0 = *(const short8*)(Qb + ((size_t)b * HW + qrow0 + l16) * C2 + quad * 8);
  short8 qf1 = *(const short8*)(Qb + ((size_t)b * HW + qrow0 + 16 + l16) * C2 + quad * 8);
  const unsigned short* kb = Kb + ((size_t)b * HW4 + wv * 1024) * C2;
  const unsigned short* vb = Vt + (size_t)b * C2 * HW4 + wv * 1024;

  short8 ones;
#pragma unroll
  for (int i = 0; i < 8; ++i) ones[i] = (short)0x3F80;  // bf16 1.0

  float4v z = {0.f, 0.f, 0.f, 0.f};
  float4v y00 = z, y10 = z, y20 = z, y01 = z, y11 = z, y21 = z;
  float4v moff = {-OFFE, -OFFE, -OFFE, -OFFE};

  KVT cur = ldkv(kb, vb, l16, quad);                       // t = 0
  KVT n1  = ldkv(kb + (size_t)32 * C2, vb + 32, l16, quad); // t = 1
#pragma unroll 2
  for (int t = 0; t < 32; ++t) {
    int tn = (t < 30) ? (t + 2) : 31;
    KVT nxt = ldkv(kb + (size_t)tn * 32 * C2, vb + tn * 32, l16, quad);

    float4v s00 = __builtin_amdgcn_mfma_f32_16x16x32_bf16(cur.ka, qf0, moff, 0, 0, 0);
    float4v s10 = __builtin_amdgcn_mfma_f32_16x16x32_bf16(cur.kh, qf0, moff, 0, 0, 0);
    float4v s01 = __builtin_amdgcn_mfma_f32_16x16x32_bf16(cur.ka, qf1, moff, 0, 0, 0);
    float4v s11 = __builtin_amdgcn_mfma_f32_16x16x32_bf16(cur.kh, qf1, moff, 0, 0, 0);

    {
      float e0 = __builtin_amdgcn_exp2f(s00[0]), e1 = __builtin_amdgcn_exp2f(s00[1]);
      float e2 = __builtin_amdgcn_exp2f(s00[2]), e3 = __builtin_amdgcn_exp2f(s00[3]);
      float f0 = __builtin_amdgcn_exp2f(s10[0]), f1 = __builtin_amdgcn_exp2f(s10[1]);
      float f2 = __builtin_amdgcn_exp2f(s10[2]), f3 = __builtin_amdgcn_exp2f(s10[3]);
      uint4v d = {packtrunc(e0, e1), packtrunc(e2, e3),
                  packtrunc(f0, f1), packtrunc(f2, f3)};
      short8 pf0 = __builtin_bit_cast(short8, d);
      y00 = __builtin_amdgcn_mfma_f32_16x16x32_bf16(pf0, cur.va, y00, 0, 0, 0);
      y10 = __builtin_amdgcn_mfma_f32_16x16x32_bf16(pf0, cur.vh, y10, 0, 0, 0);
      y20 = __builtin_amdgcn_mfma_f32_16x16x32_bf16(pf0, ones,   y20, 0, 0, 0);
    }
    {
      float e0 = __builtin_amdgcn_exp2f(s01[0]), e1 = __builtin_amdgcn_exp2f(s01[1]);
      float e2 = __builtin_amdgcn_exp2f(s01[2]), e3 = __builtin_amdgcn_exp2f(s01[3]);
      float f0 = __builtin_amdgcn_exp2f(s11[0]), f1 = __builtin_amdgcn_exp2f(s11[1]);
      float f2 = __builtin_amdgcn_exp2f(s11[2]), f3 = __builtin_amdgcn_exp2f(s11[3]);
      uint4v d = {packtrunc(e0, e1), packtrunc(e2, e3),
                  packtrunc(f0, f1), packtrunc(f2, f3)};
      short8 pf1 = __builtin_bit_cast(short8, d);
      y01 = __builtin_amdgcn_mfma_f32_16x16x32_bf16(pf1, cur.va, y01, 0, 0, 0);
      y11 = __builtin_amdgcn_mfma_f32_16x16x32_bf16(pf1, cur.vh, y11, 0, 0, 0);
      y21 = __builtin_amdgcn_mfma_f32_16x16x32_bf16(pf1, ones,   y21, 0, 0, 0);
    }
    cur = n1;
    n1 = nxt;
  }

  // y20[r]/y21[r] = per-quarter row sums l, row-aligned with y00[r]/y01[r].
  if (l16 == 0) {
#pragma unroll
    for (int r = 0; r < 4; ++r) {
      smL[wv][quad * 4 + r] = y20[r];
      smL[wv][16 + quad * 4 + r] = y21[r];
    }
  }
  if (wv > 0) {
    int pi = wv - 1;
#pragma unroll
    for (int r = 0; r < 4; ++r) {
      int lr0 = quad * 4 + r, lr1 = lr0 + 16;
      smY[pi][lr0][l16] = y00[r];  smY[pi][lr0][16 + l16] = y10[r];
      smY[pi][lr1][l16] = y01[r];  smY[pi][lr1][16 + l16] = y11[r];
    }
  }
  __syncthreads();
  if (wv == 0) {
#pragma unroll
    for (int r = 0; r < 4; ++r) {
      int lr0 = quad * 4 + r, lr1 = lr0 + 16;
      float a0 = y00[r] + smY[0][lr0][l16] + smY[1][lr0][l16] + smY[2][lr0][l16];
      float a1 = y10[r] + smY[0][lr0][16 + l16] + smY[1][lr0][16 + l16] + smY[2][lr0][16 + l16];
      float c0 = y01[r] + smY[0][lr1][l16] + smY[1][lr1][l16] + smY[2][lr1][l16];
      float c1 = y11[r] + smY[0][lr1][16 + l16] + smY[1][lr1][16 + l16] + smY[2][lr1][16 + l16];
      float L0 = smL[0][lr0] + smL[1][lr0] + smL[2][lr0] + smL[3][lr0];
      float L1 = smL[0][lr1] + smL[1][lr1] + smL[2][lr1] + smL[3][lr1];
      float inv0 = 1.f / L0, inv1 = 1.f / L1;
      size_t row0 = (size_t)b * HW + qrow0 + lr0;
      size_t row1 = (size_t)b * HW + qrow0 + lr1;
      Y[row0 * C2 + l16]      = a0 * inv0;
      Y[row0 * C2 + 16 + l16] = a1 * inv0;
      Y[row1 * C2 + l16]      = c0 * inv1;
      Y[row1 * C2 + 16 + l16] = c1 * inv1;
    }
  }
}

// ---------------------------------------------------------------------------
// Kernel 3: output conv (32->64) + bias + residual; cog split x8 (8 ch each)
// -> 2048 blocks = 8 blocks/CU (was 4). Y re-reads stay L2-resident (8 MB).
// ---------------------------------------------------------------------------
__global__ __launch_bounds__(256) void conv_out_kern(
    const float* __restrict__ Y, const float* __restrict__ x,
    const float* __restrict__ w, const float* __restrict__ bias,
    float* __restrict__ out) {
  int p = blockIdx.x * 256 + threadIdx.x;
  int cog = blockIdx.y, b = blockIdx.z;     // cog 0..7 -> channels cog*8..+7
  const float* xb = x + (size_t)b * Cin * HW + p;
  float xr[8];
#pragma unroll
  for (int i = 0; i < 8; ++i)               // residual loads in flight
    xr[i] = xb[(size_t)(cog * 8 + i) * HW];
  float y[C2];
  const float4* yp4 = (const float4*)(Y + ((size_t)b * HW + p) * C2);
#pragma unroll
  for (int i = 0; i < 8; ++i) {
    float4 t = yp4[i];
    y[4 * i] = t.x; y[4 * i + 1] = t.y; y[4 * i + 2] = t.z; y[4 * i + 3] = t.w;
  }
  float* ob = out + (size_t)b * Cin * HW + p;
#pragma unroll
  for (int i = 0; i < 8; ++i) {
    int co = cog * 8 + i;
    float s = bias[co];
#pragma unroll
    for (int o = 0; o < C2; ++o) s = fmaf(w[co * C2 + o], y[o], s);  // s_load
    ob[(size_t)co * HW] = s + xr[i];
  }
}

// ---------------------------------------------------------------------------
extern "C" void kernel_launch(void* const* d_in, const int* in_sizes, int n_in,
                              void* d_out, int out_size, void* d_ws, size_t ws_size,
                              hipStream_t stream) {
  const float* x       = (const float*)d_in[0];
  const float* w_theta = (const float*)d_in[1];
  const float* b_theta = (const float*)d_in[2];
  const float* w_phi   = (const float*)d_in[3];
  const float* b_phi   = (const float*)d_in[4];
  const float* w_g     = (const float*)d_in[5];
  const float* b_g     = (const float*)d_in[6];
  const float* w_out   = (const float*)d_in[7];
  const float* b_out   = (const float*)d_in[8];
  float* out = (float*)d_out;

  float* Yws = (float*)d_ws;                                   // 8 MB fp32
  unsigned short* Qb = (unsigned short*)(Yws + (size_t)4 * HW * C2);
  unsigned short* Kb = Qb + (size_t)4 * HW * C2;
  unsigned short* Vt = Kb + (size_t)4 * HW4 * C2;
  float* wAll = (float*)(Vt + (size_t)4 * HW4 * C2);           // 6144 f
  float* bAll = wAll + 6144;                                   // 96 f

  repack_w_kern<<<25, 256, 0, stream>>>(w_theta, b_theta, w_phi, b_phi,
                                        w_g, b_g, wAll, bAll);
  conv_qkv_kern<<<dim3(64, 4, 4), 256, 0, stream>>>(x, wAll, bAll, Qb, Kb, Vt);
  attn_mfma_kern<<<dim3(HW / 32, 4), 256, 0, stream>>>(Qb, Kb, Vt, Yws);
  conv_out_kern<<<dim3(64, 8, 4), 256, 0, stream>>>(Yws, x, w_out, b_out, out);
}